// Round 7
// baseline (349.856 us; speedup 1.0000x reference)
//
#include <hip/hip_runtime.h>

#define BATCH 4
#define HH 1024
#define WW 1024

// ---------------- fused downsample(1024->256) + conv0 (3->8, s2, relu) -------
__global__ __launch_bounds__(256) void dsconv0_k(const float* __restrict__ img,
                                                 const float* __restrict__ wgt,
                                                 const float* __restrict__ bias,
                                                 float* __restrict__ out) {
  int blk = blockIdx.x;            // b*64 + ty*8 + tx
  int tx = blk & 7;
  int ty = (blk >> 3) & 7;
  int b = blk >> 6;
  int t = threadIdx.x;

  __shared__ float low[3][33][36];  // padded row stride 36

  int Y0 = ty << 4, X0 = tx << 4;  // output tile origin (128x128 space)
  int gy0 = 2 * Y0 - 1, gx0 = 2 * X0 - 1;  // low-res support origin

  for (int i = t; i < 3 * 33 * 33; i += 256) {
    int c = i / 1089;
    int rem = i - c * 1089;
    int ly = rem / 33;
    int lx = rem - ly * 33;
    int gy = gy0 + ly, gx = gx0 + lx;
    float v = 0.f;
    if (gy >= 0 && gx >= 0) {
      const float* p = img + (size_t)(b * 3 + c) * HH * WW + (4 * gy + 1) * WW + 4 * gx + 1;
      v = 0.25f * (p[0] + p[1] + p[WW] + p[WW + 1]);
    }
    low[c][ly][lx] = v;
  }
  __syncthreads();

  int x = t & 15, y = t >> 4;
  float acc[8];
#pragma unroll
  for (int o = 0; o < 8; ++o) acc[o] = bias[o];
  for (int ci = 0; ci < 3; ++ci) {
#pragma unroll
    for (int ky = 0; ky < 3; ++ky) {
#pragma unroll
      for (int kx = 0; kx < 3; ++kx) {
        float v = low[ci][2 * y + ky][2 * x + kx];
#pragma unroll
        for (int o = 0; o < 8; ++o)
          acc[o] += wgt[o * 27 + ci * 9 + ky * 3 + kx] * v;
      }
    }
  }
  float* ob = out + (size_t)b * 8 * 128 * 128 + (Y0 + y) * 128 + X0 + x;
#pragma unroll
  for (int o = 0; o < 8; ++o) ob[o * 128 * 128] = fmaxf(acc[o], 0.f);
}

// ---------------- LDS-tiled 3x3 s2 conv, 16x16 output tile, all CO/thread ----
template <int CI, int CO, int HI>
__global__ __launch_bounds__(256) void conv_tile16_k(const float* __restrict__ in,
                                                     const float* __restrict__ wgt,
                                                     const float* __restrict__ bias,
                                                     float* __restrict__ out) {
  const int HO = HI / 2;
  const int NT = HO / 16;
  int blk = blockIdx.x;
  int tx = blk % NT;
  int ty = (blk / NT) % NT;
  int b = blk / (NT * NT);
  int t = threadIdx.x;

  __shared__ float s[CI][33][36];

  int Y0 = ty << 4, X0 = tx << 4;
  int gy0 = 2 * Y0 - 1, gx0 = 2 * X0 - 1;

  for (int i = t; i < CI * 33 * 33; i += 256) {
    int c = i / 1089;
    int rem = i - c * 1089;
    int ly = rem / 33;
    int lx = rem - ly * 33;
    int gy = gy0 + ly, gx = gx0 + lx;
    float v = 0.f;
    if (gy >= 0 && gy < HI && gx >= 0 && gx < HI)
      v = in[((size_t)(b * CI + c) * HI + gy) * HI + gx];
    s[c][ly][lx] = v;
  }
  __syncthreads();

  int x = t & 15, y = t >> 4;
  float acc[CO];
#pragma unroll
  for (int o = 0; o < CO; ++o) acc[o] = bias[o];
  for (int ci = 0; ci < CI; ++ci) {
#pragma unroll
    for (int ky = 0; ky < 3; ++ky) {
#pragma unroll
      for (int kx = 0; kx < 3; ++kx) {
        float v = s[ci][2 * y + ky][2 * x + kx];
#pragma unroll
        for (int o = 0; o < CO; ++o)
          acc[o] += wgt[(o * CI + ci) * 9 + ky * 3 + kx] * v;
      }
    }
  }
  float* ob = out + (size_t)b * CO * HO * HO + (Y0 + y) * HO + X0 + x;
#pragma unroll
  for (int o = 0; o < CO; ++o) ob[(size_t)o * HO * HO] = fmaxf(acc[o], 0.f);
}

// ---------------- LDS-tiled 3x3 s2 conv, 8x8 output tile, 4-way o-split ------
template <int CI, int CO, int HI>
__global__ __launch_bounds__(256) void conv_tile8_k(const float* __restrict__ in,
                                                    const float* __restrict__ wgt,
                                                    const float* __restrict__ bias,
                                                    float* __restrict__ out) {
  const int HO = HI / 2;
  const int NT = HO / 8;
  const int NO = CO / 4;
  int blk = blockIdx.x;
  int tx = blk % NT;
  int ty = (blk / NT) % NT;
  int b = blk / (NT * NT);
  int t = threadIdx.x;

  __shared__ float s[CI][17][20];

  int Y0 = ty << 3, X0 = tx << 3;
  int gy0 = 2 * Y0 - 1, gx0 = 2 * X0 - 1;

  for (int i = t; i < CI * 17 * 17; i += 256) {
    int c = i / 289;
    int rem = i - c * 289;
    int ly = rem / 17;
    int lx = rem - ly * 17;
    int gy = gy0 + ly, gx = gx0 + lx;
    float v = 0.f;
    if (gy >= 0 && gy < HI && gx >= 0 && gx < HI)
      v = in[((size_t)(b * CI + c) * HI + gy) * HI + gx];
    s[c][ly][lx] = v;
  }
  __syncthreads();

  int px = t & 63;
  int x = px & 7, y = px >> 3;
  int og = t >> 6;  // 0..3
  float acc[NO];
#pragma unroll
  for (int j = 0; j < NO; ++j) acc[j] = bias[og * NO + j];
  for (int ci = 0; ci < CI; ++ci) {
#pragma unroll
    for (int ky = 0; ky < 3; ++ky) {
#pragma unroll
      for (int kx = 0; kx < 3; ++kx) {
        float v = s[ci][2 * y + ky][2 * x + kx];
#pragma unroll
        for (int j = 0; j < NO; ++j)
          acc[j] += wgt[((og * NO + j) * CI + ci) * 9 + ky * 3 + kx] * v;
      }
    }
  }
#pragma unroll
  for (int j = 0; j < NO; ++j)
    out[(size_t)(b * CO + og * NO + j) * HO * HO + (Y0 + y) * HO + X0 + x] =
        fmaxf(acc[j], 0.f);
}

// ---------------- global path from x3: composed splat + cpool + 2 FC ----------
__global__ __launch_bounds__(256) void cpfc_k(const float* __restrict__ x3,
                                              const float* __restrict__ spw,
                                              const float* __restrict__ spb,
                                              const float* __restrict__ val,
                                              const float* __restrict__ cw,
                                              const float* __restrict__ cb,
                                              const float* __restrict__ fw1,
                                              const float* __restrict__ fb1,
                                              const float* __restrict__ fw2,
                                              const float* __restrict__ fb2,
                                              float* __restrict__ fc2o) {
  __shared__ float eff[4][64];
  __shared__ float eb[4][4];
  __shared__ float sc[256];
  __shared__ float h1[256];
  int t = threadIdx.x;

  {  // eff[ch][k] = sum_c cw[ch][c] * spw[c][k]
    int ch = t >> 6, k = t & 63;
    float a = 0.f;
#pragma unroll 8
    for (int c = 0; c < 64; ++c) a += cw[ch * 64 + c] * spw[c * 64 + k];
    eff[ch][k] = a;
  }
  if (t < 16) {  // eb[b][ch] = cb[ch] + sum_c cw[ch][c]*(spb[c]+val[b])
    int b = t >> 2, ch = t & 3;
    float a = cb[ch];
    float vb = val[b];
#pragma unroll 8
    for (int c = 0; c < 64; ++c) a += cw[ch * 64 + c] * (spb[c] + vb);
    eb[b][ch] = a;
  }
  __syncthreads();

  int b = t >> 6;
  int r = t & 63;
  int ch = r >> 4;
  int py = (r >> 2) & 3;
  int px = r & 3;
  float sum = 0.f;
  for (int dy = 0; dy < 2; ++dy)
    for (int dx = 0; dx < 2; ++dx) {
      int p = (py * 2 + dy) * 32 + (px * 2 + dx) * 2;  // ::2,::2 of 16x16
      float acc = eb[b][ch];
      const float* xb = x3 + ((size_t)b * 64) * 256 + p;
#pragma unroll 8
      for (int k = 0; k < 64; ++k) acc += eff[ch][k] * xb[k * 256];
      sum += fmaxf(acc, 0.f);
    }
  sc[t] = sum * 0.25f;
  __syncthreads();
  int o = t & 63;
  float acc = fb1[o];
#pragma unroll 8
  for (int k = 0; k < 64; ++k) acc += fw1[o * 64 + k] * sc[b * 64 + k];
  h1[t] = fmaxf(acc, 0.f);
  __syncthreads();
  acc = fb2[o];
#pragma unroll 8
  for (int k = 0; k < 64; ++k) acc += fw2[o * 64 + k] * h1[b * 64 + k];
  fc2o[t] = fmaxf(acc, 0.f);
}

// ---------------- fused pointwise chain: splat->loc1->loc2->loc3->coeff -------
template <int CI, int CO, int RELU>
__device__ __forceinline__ void pw_tile(const float (*__restrict__ X)[36],
                                        float (*__restrict__ Y)[36],
                                        const float* __restrict__ w,
                                        const float* __restrict__ bias,
                                        float badd, int t) {
  constexpr int NO = CO / 32;
  int pg = (t & 7) << 2;
  int og = t >> 3;
  float acc[NO][4];
#pragma unroll
  for (int j = 0; j < NO; ++j) {
    float bb = bias[og * NO + j] + badd;
#pragma unroll
    for (int u = 0; u < 4; ++u) acc[j][u] = bb;
  }
#pragma unroll 4
  for (int k = 0; k < CI; k += 4) {
    float4 xv0 = *(const float4*)&X[k][pg];
    float4 xv1 = *(const float4*)&X[k + 1][pg];
    float4 xv2 = *(const float4*)&X[k + 2][pg];
    float4 xv3 = *(const float4*)&X[k + 3][pg];
#pragma unroll
    for (int j = 0; j < NO; ++j) {
      float4 wv = *(const float4*)&w[(og * NO + j) * CI + k];
      acc[j][0] += wv.x * xv0.x + wv.y * xv1.x + wv.z * xv2.x + wv.w * xv3.x;
      acc[j][1] += wv.x * xv0.y + wv.y * xv1.y + wv.z * xv2.y + wv.w * xv3.y;
      acc[j][2] += wv.x * xv0.z + wv.y * xv1.z + wv.z * xv2.z + wv.w * xv3.z;
      acc[j][3] += wv.x * xv0.w + wv.y * xv1.w + wv.z * xv2.w + wv.w * xv3.w;
    }
  }
#pragma unroll
  for (int j = 0; j < NO; ++j) {
    int o = og * NO + j;
#pragma unroll
    for (int u = 0; u < 4; ++u) {
      float v = acc[j][u];
      if (RELU) v = fmaxf(v, 0.f);
      Y[o][pg + u] = v;
    }
  }
}

__global__ __launch_bounds__(256) void mlp_k(
    const float* __restrict__ x3, const float* __restrict__ spw,
    const float* __restrict__ spb, const float* __restrict__ val,
    const float* __restrict__ lw1, const float* __restrict__ lb1,
    const float* __restrict__ lw2, const float* __restrict__ lb2,
    const float* __restrict__ lw3, const float* __restrict__ lb3,
    const float* __restrict__ fc2o, const float* __restrict__ gw,
    const float* __restrict__ gb, float* __restrict__ gridt) {
  int blk = blockIdx.x;  // b*8 + pg
  int b = blk >> 3;
  int p0 = (blk & 7) << 5;
  int t = threadIdx.x;

  __shared__ float A[128][36];
  __shared__ float Bf[128][36];

  for (int i = t; i < 64 * 32; i += 256) {
    int c = i >> 5, p = i & 31;
    A[c][p] = x3[((size_t)(b * 64 + c)) * 256 + p0 + p];
  }
  __syncthreads();

  pw_tile<64, 64, 0>(A, Bf, spw, spb, val[b], t);   // splat (no relu)
  __syncthreads();
  pw_tile<64, 128, 1>(Bf, A, lw1, lb1, 0.f, t);     // loc1
  __syncthreads();
  pw_tile<128, 128, 1>(A, Bf, lw2, lb2, 0.f, t);    // loc2
  __syncthreads();
  pw_tile<128, 64, 1>(Bf, A, lw3, lb3, 0.f, t);     // loc3
  __syncthreads();

  {
    int pg = (t & 7) << 2;
    int og = t >> 3;  // NO = 3
    float acc[3][4];
#pragma unroll
    for (int j = 0; j < 3; ++j) {
      float bb = gb[og * 3 + j];
#pragma unroll
      for (int u = 0; u < 4; ++u) acc[j][u] = bb;
    }
    const float* cv = fc2o + b * 64;
#pragma unroll 4
    for (int k = 0; k < 64; k += 4) {
      float4 cc4 = *(const float4*)&cv[k];
      float4 xv0 = *(const float4*)&A[k][pg];
      float4 xv1 = *(const float4*)&A[k + 1][pg];
      float4 xv2 = *(const float4*)&A[k + 2][pg];
      float4 xv3 = *(const float4*)&A[k + 3][pg];
      xv0.x = fmaxf(xv0.x + cc4.x, 0.f); xv0.y = fmaxf(xv0.y + cc4.x, 0.f);
      xv0.z = fmaxf(xv0.z + cc4.x, 0.f); xv0.w = fmaxf(xv0.w + cc4.x, 0.f);
      xv1.x = fmaxf(xv1.x + cc4.y, 0.f); xv1.y = fmaxf(xv1.y + cc4.y, 0.f);
      xv1.z = fmaxf(xv1.z + cc4.y, 0.f); xv1.w = fmaxf(xv1.w + cc4.y, 0.f);
      xv2.x = fmaxf(xv2.x + cc4.z, 0.f); xv2.y = fmaxf(xv2.y + cc4.z, 0.f);
      xv2.z = fmaxf(xv2.z + cc4.z, 0.f); xv2.w = fmaxf(xv2.w + cc4.z, 0.f);
      xv3.x = fmaxf(xv3.x + cc4.w, 0.f); xv3.y = fmaxf(xv3.y + cc4.w, 0.f);
      xv3.z = fmaxf(xv3.z + cc4.w, 0.f); xv3.w = fmaxf(xv3.w + cc4.w, 0.f);
#pragma unroll
      for (int j = 0; j < 3; ++j) {
        float4 wv = *(const float4*)&gw[(og * 3 + j) * 64 + k];
        acc[j][0] += wv.x * xv0.x + wv.y * xv1.x + wv.z * xv2.x + wv.w * xv3.x;
        acc[j][1] += wv.x * xv0.y + wv.y * xv1.y + wv.z * xv2.y + wv.w * xv3.y;
        acc[j][2] += wv.x * xv0.z + wv.y * xv1.z + wv.z * xv2.z + wv.w * xv3.z;
        acc[j][3] += wv.x * xv0.w + wv.y * xv1.w + wv.z * xv2.w + wv.w * xv3.w;
      }
    }
#pragma unroll
    for (int j = 0; j < 3; ++j) {
      int o = og * 3 + j;
      int l = o / 12, cc = o - l * 12;
#pragma unroll
      for (int u = 0; u < 4; ++u)
        gridt[(size_t)(((b * 8 + l) << 8) + p0 + pg + u) * 12 + cc] = acc[j][u];
    }
  }
}

// ---------------- guide + bilateral slice + affine apply (fused, LDS grid) ----
#define ZST 200
__global__ __launch_bounds__(256) void slice_k(
    const float* __restrict__ img, const float* __restrict__ gridt,
    const float* __restrict__ ccm_w, const float* __restrict__ ccm_b,
    const float* __restrict__ shifts, const float* __restrict__ slopes,
    const float* __restrict__ prw, const float* __restrict__ prb,
    float* __restrict__ out) {
  int blk = blockIdx.x;          // BATCH*1024
  int b = blk >> 10;
  int h = blk & 1023;
  int t = threadIdx.x;

  __shared__ float sg[8 * ZST];      // 6400 B
  __shared__ float2 lut[3][16];      // CS, CB

  float cy = (h + 0.5f) * 0.015625f - 0.5f;
  float y0f = floorf(cy);
  float wy = cy - y0f;
  int y0 = (int)y0f;
  int yi0 = min(max(y0, 0), 15), yi1 = min(max(y0 + 1, 0), 15);

  if (t < 48) {  // build curve LUT (prefix sums over 16 knots)
    int c = t >> 4, k = t & 15;
    float cs = 0.f, cbv = 0.f;
    for (int i = 0; i <= k; ++i) {
      float s = slopes[c * 16 + i];
      cs += s;
      cbv += s * shifts[c * 16 + i];
    }
    lut[c][k] = make_float2(cs, cbv);
  }

  // stage y-lerped grid: 8 slabs x 48 float4
  for (int i = t; i < 384; i += 256) {
    int z = i / 48;
    int e = i - z * 48;
    const float4* s0 =
        (const float4*)(gridt + (size_t)(((b * 8 + z) << 8) + (yi0 << 4)) * 12);
    const float4* s1 =
        (const float4*)(gridt + (size_t)(((b * 8 + z) << 8) + (yi1 << 4)) * 12);
    float4 a = s0[e], c = s1[e];
    float4 v = make_float4(a.x + wy * (c.x - a.x), a.y + wy * (c.y - a.y),
                           a.z + wy * (c.z - a.z), a.w + wy * (c.w - a.w));
    *((float4*)(sg + z * ZST) + e) = v;
  }
  __syncthreads();

  int pp = (h << 10) + (t << 2);
  const float* ib = img + (size_t)b * 3 * HH * WW;
  float4 R4 = *(const float4*)(ib + pp);
  float4 G4 = *(const float4*)(ib + HH * WW + pp);
  float4 B4 = *(const float4*)(ib + 2 * HH * WW + pp);
  float r_[4] = {R4.x, R4.y, R4.z, R4.w};
  float g_[4] = {G4.x, G4.y, G4.z, G4.w};
  float b_[4] = {B4.x, B4.y, B4.z, B4.w};

  float m0 = ccm_w[0], m1 = ccm_w[1], m2 = ccm_w[2];
  float m3 = ccm_w[3], m4 = ccm_w[4], m5 = ccm_w[5];
  float m6 = ccm_w[6], m7 = ccm_w[7], m8 = ccm_w[8];
  float c0 = ccm_b[0], c1 = ccm_b[1], c2 = ccm_b[2];
  float p0 = prw[0], p1 = prw[1], p2 = prw[2], pb = prb[0];

  float base0 = shifts[0], base1 = shifts[16], base2 = shifts[32];
  float inv0 = 1.0f / (shifts[1] - base0);
  float inv1 = 1.0f / (shifts[17] - base1);
  float inv2 = 1.0f / (shifts[33] - base2);

  float ro[4], go[4], bo[4];
#pragma unroll
  for (int j = 0; j < 4; ++j) {
    float r = r_[j], g = g_[j], bl = b_[j];
    float v0 = c0 + m0 * r + m1 * g + m2 * bl;
    float v1 = c1 + m3 * r + m4 * g + m5 * bl;
    float v2 = c2 + m6 * r + m7 * g + m8 * bl;

    float tv0 = fmaxf(v0, base0);
    float tv1 = fmaxf(v1, base1);
    float tv2 = fmaxf(v2, base2);
    int j0 = min((int)((tv0 - base0) * inv0), 15);
    int j1 = min((int)((tv1 - base1) * inv1), 15);
    int j2 = min((int)((tv2 - base2) * inv2), 15);
    float2 e0 = lut[0][j0];
    float2 e1 = lut[1][j1];
    float2 e2 = lut[2][j2];
    float f0 = e0.x * tv0 - e0.y;
    float f1 = e1.x * tv1 - e1.y;
    float f2 = e2.x * tv2 - e2.y;

    float gg = pb + p0 * f0 + p1 * f1 + p2 * f2;
    float guide = fminf(fmaxf(gg, 0.f), 1.f);

    int w = (t << 2) + j;
    float cx = (w + 0.5f) * 0.015625f - 0.5f;
    float x0f = floorf(cx);
    float wx = cx - x0f;
    int x0i = (int)x0f;
    int xi0 = min(max(x0i, 0), 15), xi1 = min(max(x0i + 1, 0), 15);

    float cz = guide * 8.0f - 0.5f;
    float z0f = floorf(cz);
    float wz = cz - z0f;
    int z0i = (int)z0f;
    int zi0 = min(max(z0i, 0), 7), zi1 = min(max(z0i + 1, 0), 7);

    int oz0 = zi0 * ZST, oz1 = zi1 * ZST;
    int ox0 = xi0 * 12, ox1 = xi1 * 12;
    float wz1 = wz, wz0 = 1.f - wz;
    float wx1 = wx, wx0 = 1.f - wx;

    float acc[12];
#pragma unroll
    for (int k = 0; k < 12; ++k) acc[k] = 0.f;

#pragma unroll
    for (int dz = 0; dz < 2; ++dz) {
      int oz = dz ? oz1 : oz0;
      float wzz = dz ? wz1 : wz0;
#pragma unroll
      for (int dx = 0; dx < 2; ++dx) {
        int ox = dx ? ox1 : ox0;
        float wgt = wzz * (dx ? wx1 : wx0);
        const float* gp = sg + oz + ox;
        float4 a0 = *(const float4*)gp;
        float4 a1 = *(const float4*)(gp + 4);
        float4 a2 = *(const float4*)(gp + 8);
        acc[0] += wgt * a0.x;  acc[1] += wgt * a0.y;
        acc[2] += wgt * a0.z;  acc[3] += wgt * a0.w;
        acc[4] += wgt * a1.x;  acc[5] += wgt * a1.y;
        acc[6] += wgt * a1.z;  acc[7] += wgt * a1.w;
        acc[8] += wgt * a2.x;  acc[9] += wgt * a2.y;
        acc[10] += wgt * a2.z; acc[11] += wgt * a2.w;
      }
    }
    ro[j] = acc[0] * r + acc[1] * g + acc[2] * bl + acc[3];
    go[j] = acc[4] * r + acc[5] * g + acc[6] * bl + acc[7];
    bo[j] = acc[8] * r + acc[9] * g + acc[10] * bl + acc[11];
  }
  float* ob = out + (size_t)b * 3 * HH * WW;
  *(float4*)(ob + pp) = make_float4(ro[0], ro[1], ro[2], ro[3]);
  *(float4*)(ob + HH * WW + pp) = make_float4(go[0], go[1], go[2], go[3]);
  *(float4*)(ob + 2 * HH * WW + pp) = make_float4(bo[0], bo[1], bo[2], bo[3]);
}

extern "C" void kernel_launch(void* const* d_in, const int* in_sizes, int n_in,
                              void* d_out, int out_size, void* d_ws, size_t ws_size,
                              hipStream_t stream) {
  const float* image = (const float*)d_in[0];
  const float* val   = (const float*)d_in[1];
  const float* sw0 = (const float*)d_in[2];  const float* sb0 = (const float*)d_in[3];
  const float* sw1 = (const float*)d_in[4];  const float* sb1 = (const float*)d_in[5];
  const float* sw2 = (const float*)d_in[6];  const float* sb2 = (const float*)d_in[7];
  const float* sw3 = (const float*)d_in[8];  const float* sb3 = (const float*)d_in[9];
  const float* spw = (const float*)d_in[10]; const float* spb = (const float*)d_in[11];
  const float* lw1 = (const float*)d_in[12]; const float* lb1 = (const float*)d_in[13];
  const float* lw2 = (const float*)d_in[14]; const float* lb2 = (const float*)d_in[15];
  const float* lw3 = (const float*)d_in[16]; const float* lb3 = (const float*)d_in[17];
  const float* cw  = (const float*)d_in[18]; const float* cb  = (const float*)d_in[19];
  const float* fw1 = (const float*)d_in[20]; const float* fb1 = (const float*)d_in[21];
  const float* fw2 = (const float*)d_in[22]; const float* fb2 = (const float*)d_in[23];
  const float* gw  = (const float*)d_in[24]; const float* gb  = (const float*)d_in[25];
  const float* ccm_w = (const float*)d_in[26]; const float* ccm_b = (const float*)d_in[27];
  const float* shifts = (const float*)d_in[28]; const float* slopes = (const float*)d_in[29];
  const float* prw = (const float*)d_in[30]; const float* prb = (const float*)d_in[31];
  float* out = (float*)d_out;

  float* ws    = (float*)d_ws;
  float* x0    = ws;                  // 524288
  float* x1    = x0 + 524288;         // 262144
  float* x2    = x1 + 262144;         // 131072
  float* x3    = x2 + 131072;         // 65536
  float* fc2o  = x3 + 65536;          // 256
  float* gridt = fc2o + 256;          // 98304

  dsconv0_k<<<256, 256, 0, stream>>>(image, sw0, sb0, x0);
  conv_tile16_k<8, 16, 128><<<64, 256, 0, stream>>>(x0, sw1, sb1, x1);
  conv_tile8_k<16, 32, 64><<<64, 256, 0, stream>>>(x1, sw2, sb2, x2);
  conv_tile8_k<32, 64, 32><<<16, 256, 0, stream>>>(x2, sw3, sb3, x3);
  cpfc_k<<<1, 256, 0, stream>>>(x3, spw, spb, val, cw, cb, fw1, fb1, fw2, fb2,
                                fc2o);
  mlp_k<<<32, 256, 0, stream>>>(x3, spw, spb, val, lw1, lb1, lw2, lb2, lw3, lb3,
                                fc2o, gw, gb, gridt);
  slice_k<<<4096, 256, 0, stream>>>(image, gridt, ccm_w, ccm_b, shifts, slopes,
                                    prw, prb, out);
}

// Round 8
// 276.668 us; speedup vs baseline: 1.2645x; 1.2645x over previous
//
#include <hip/hip_runtime.h>

#define BATCH 4
#define HH 1024
#define WW 1024

// ---------------- fused downsample(1024->256) + conv0 (3->8, s2, relu) -------
__global__ __launch_bounds__(256) void dsconv0_k(const float* __restrict__ img,
                                                 const float* __restrict__ wgt,
                                                 const float* __restrict__ bias,
                                                 float* __restrict__ out) {
  int blk = blockIdx.x;            // b*64 + ty*8 + tx
  int tx = blk & 7;
  int ty = (blk >> 3) & 7;
  int b = blk >> 6;
  int t = threadIdx.x;

  __shared__ float low[3][33][36];  // padded row stride 36

  int Y0 = ty << 4, X0 = tx << 4;  // output tile origin (128x128 space)
  int gy0 = 2 * Y0 - 1, gx0 = 2 * X0 - 1;  // low-res support origin

  for (int i = t; i < 3 * 33 * 33; i += 256) {
    int c = i / 1089;
    int rem = i - c * 1089;
    int ly = rem / 33;
    int lx = rem - ly * 33;
    int gy = gy0 + ly, gx = gx0 + lx;
    float v = 0.f;
    if (gy >= 0 && gx >= 0) {
      const float* p = img + (size_t)(b * 3 + c) * HH * WW + (4 * gy + 1) * WW + 4 * gx + 1;
      v = 0.25f * (p[0] + p[1] + p[WW] + p[WW + 1]);
    }
    low[c][ly][lx] = v;
  }
  __syncthreads();

  int x = t & 15, y = t >> 4;
  float acc[8];
#pragma unroll
  for (int o = 0; o < 8; ++o) acc[o] = bias[o];
  for (int ci = 0; ci < 3; ++ci) {
#pragma unroll
    for (int ky = 0; ky < 3; ++ky) {
#pragma unroll
      for (int kx = 0; kx < 3; ++kx) {
        float v = low[ci][2 * y + ky][2 * x + kx];
#pragma unroll
        for (int o = 0; o < 8; ++o)
          acc[o] += wgt[o * 27 + ci * 9 + ky * 3 + kx] * v;
      }
    }
  }
  float* ob = out + (size_t)b * 8 * 128 * 128 + (Y0 + y) * 128 + X0 + x;
#pragma unroll
  for (int o = 0; o < 8; ++o) ob[o * 128 * 128] = fmaxf(acc[o], 0.f);
}

// ---------------- LDS-tiled 3x3 s2 conv, PxP output tile ---------------------
// Blocks = BATCH * (HO/P)^2; choose P so that's >= 256 (latency hiding!).
// 256 threads = P*P pixels x (256/(P*P)) channel-groups, NO = CO*P*P/256
// outputs per thread.
template <int CI, int CO, int HI, int P>
__global__ __launch_bounds__(256) void conv_tile_k(const float* __restrict__ in,
                                                   const float* __restrict__ wgt,
                                                   const float* __restrict__ bias,
                                                   float* __restrict__ out) {
  const int HO = HI / 2;
  const int NT = HO / P;
  const int HALO = 2 * P + 1;
  const int RS = 2 * P + 4;       // padded row stride
  constexpr int NO = (CO * P * P) / 256;
  int blk = blockIdx.x;
  int tx = blk % NT;
  int ty = (blk / NT) % NT;
  int b = blk / (NT * NT);
  int t = threadIdx.x;

  __shared__ float s[CI][HALO][RS];

  int Y0 = ty * P, X0 = tx * P;
  int gy0 = 2 * Y0 - 1, gx0 = 2 * X0 - 1;

  for (int i = t; i < CI * HALO * HALO; i += 256) {
    int c = i / (HALO * HALO);
    int rem = i - c * (HALO * HALO);
    int ly = rem / HALO;
    int lx = rem - ly * HALO;
    int gy = gy0 + ly, gx = gx0 + lx;
    float v = 0.f;
    if (gy >= 0 && gy < HI && gx >= 0 && gx < HI)
      v = in[((size_t)(b * CI + c) * HI + gy) * HI + gx];
    s[c][ly][lx] = v;
  }
  __syncthreads();

  int px = t % (P * P);
  int og = t / (P * P);
  int x = px % P, y = px / P;
  float acc[NO];
#pragma unroll
  for (int j = 0; j < NO; ++j) acc[j] = bias[og * NO + j];
  for (int ci = 0; ci < CI; ++ci) {
#pragma unroll
    for (int ky = 0; ky < 3; ++ky) {
#pragma unroll
      for (int kx = 0; kx < 3; ++kx) {
        float v = s[ci][2 * y + ky][2 * x + kx];
#pragma unroll
        for (int j = 0; j < NO; ++j)
          acc[j] += wgt[((og * NO + j) * CI + ci) * 9 + ky * 3 + kx] * v;
      }
    }
  }
#pragma unroll
  for (int j = 0; j < NO; ++j)
    out[(size_t)(b * CO + og * NO + j) * HO * HO + (Y0 + y) * HO + X0 + x] =
        fmaxf(acc[j], 0.f);
}

// ---------------- global path from x3: composed splat + cpool + 2 FC ----------
__global__ __launch_bounds__(256) void cpfc_k(const float* __restrict__ x3,
                                              const float* __restrict__ spw,
                                              const float* __restrict__ spb,
                                              const float* __restrict__ val,
                                              const float* __restrict__ cw,
                                              const float* __restrict__ cb,
                                              const float* __restrict__ fw1,
                                              const float* __restrict__ fb1,
                                              const float* __restrict__ fw2,
                                              const float* __restrict__ fb2,
                                              float* __restrict__ fc2o) {
  __shared__ float eff[4][64];
  __shared__ float eb[4][4];
  __shared__ float sc[256];
  __shared__ float h1[256];
  int t = threadIdx.x;

  {  // eff[ch][k] = sum_c cw[ch][c] * spw[c][k]
    int ch = t >> 6, k = t & 63;
    float a = 0.f;
#pragma unroll 8
    for (int c = 0; c < 64; ++c) a += cw[ch * 64 + c] * spw[c * 64 + k];
    eff[ch][k] = a;
  }
  if (t < 16) {  // eb[b][ch] = cb[ch] + sum_c cw[ch][c]*(spb[c]+val[b])
    int b = t >> 2, ch = t & 3;
    float a = cb[ch];
    float vb = val[b];
#pragma unroll 8
    for (int c = 0; c < 64; ++c) a += cw[ch * 64 + c] * (spb[c] + vb);
    eb[b][ch] = a;
  }
  __syncthreads();

  int b = t >> 6;
  int r = t & 63;
  int ch = r >> 4;
  int py = (r >> 2) & 3;
  int px = r & 3;
  float sum = 0.f;
  for (int dy = 0; dy < 2; ++dy)
    for (int dx = 0; dx < 2; ++dx) {
      int p = (py * 2 + dy) * 32 + (px * 2 + dx) * 2;  // ::2,::2 of 16x16
      float acc = eb[b][ch];
      const float* xb = x3 + ((size_t)b * 64) * 256 + p;
#pragma unroll 8
      for (int k = 0; k < 64; ++k) acc += eff[ch][k] * xb[k * 256];
      sum += fmaxf(acc, 0.f);
    }
  sc[t] = sum * 0.25f;
  __syncthreads();
  int o = t & 63;
  float acc = fb1[o];
#pragma unroll 8
  for (int k = 0; k < 64; ++k) acc += fw1[o * 64 + k] * sc[b * 64 + k];
  h1[t] = fmaxf(acc, 0.f);
  __syncthreads();
  acc = fb2[o];
#pragma unroll 8
  for (int k = 0; k < 64; ++k) acc += fw2[o * 64 + k] * h1[b * 64 + k];
  fc2o[t] = fmaxf(acc, 0.f);
}

// ---------------- fused pointwise chain: splat->loc1->loc2->loc3->coeff -------
template <int CI, int CO, int RELU>
__device__ __forceinline__ void pw_tile(const float (*__restrict__ X)[36],
                                        float (*__restrict__ Y)[36],
                                        const float* __restrict__ w,
                                        const float* __restrict__ bias,
                                        float badd, int t) {
  constexpr int NO = CO / 32;
  int pg = (t & 7) << 2;
  int og = t >> 3;
  float acc[NO][4];
#pragma unroll
  for (int j = 0; j < NO; ++j) {
    float bb = bias[og * NO + j] + badd;
#pragma unroll
    for (int u = 0; u < 4; ++u) acc[j][u] = bb;
  }
#pragma unroll 4
  for (int k = 0; k < CI; k += 4) {
    float4 xv0 = *(const float4*)&X[k][pg];
    float4 xv1 = *(const float4*)&X[k + 1][pg];
    float4 xv2 = *(const float4*)&X[k + 2][pg];
    float4 xv3 = *(const float4*)&X[k + 3][pg];
#pragma unroll
    for (int j = 0; j < NO; ++j) {
      float4 wv = *(const float4*)&w[(og * NO + j) * CI + k];
      acc[j][0] += wv.x * xv0.x + wv.y * xv1.x + wv.z * xv2.x + wv.w * xv3.x;
      acc[j][1] += wv.x * xv0.y + wv.y * xv1.y + wv.z * xv2.y + wv.w * xv3.y;
      acc[j][2] += wv.x * xv0.z + wv.y * xv1.z + wv.z * xv2.z + wv.w * xv3.z;
      acc[j][3] += wv.x * xv0.w + wv.y * xv1.w + wv.z * xv2.w + wv.w * xv3.w;
    }
  }
#pragma unroll
  for (int j = 0; j < NO; ++j) {
    int o = og * NO + j;
#pragma unroll
    for (int u = 0; u < 4; ++u) {
      float v = acc[j][u];
      if (RELU) v = fmaxf(v, 0.f);
      Y[o][pg + u] = v;
    }
  }
}

__global__ __launch_bounds__(256) void mlp_k(
    const float* __restrict__ x3, const float* __restrict__ spw,
    const float* __restrict__ spb, const float* __restrict__ val,
    const float* __restrict__ lw1, const float* __restrict__ lb1,
    const float* __restrict__ lw2, const float* __restrict__ lb2,
    const float* __restrict__ lw3, const float* __restrict__ lb3,
    const float* __restrict__ fc2o, const float* __restrict__ gw,
    const float* __restrict__ gb, float* __restrict__ gridt) {
  int blk = blockIdx.x;  // b*8 + pg
  int b = blk >> 3;
  int p0 = (blk & 7) << 5;
  int t = threadIdx.x;

  __shared__ float A[128][36];
  __shared__ float Bf[128][36];

  for (int i = t; i < 64 * 32; i += 256) {
    int c = i >> 5, p = i & 31;
    A[c][p] = x3[((size_t)(b * 64 + c)) * 256 + p0 + p];
  }
  __syncthreads();

  pw_tile<64, 64, 0>(A, Bf, spw, spb, val[b], t);   // splat (no relu)
  __syncthreads();
  pw_tile<64, 128, 1>(Bf, A, lw1, lb1, 0.f, t);     // loc1
  __syncthreads();
  pw_tile<128, 128, 1>(A, Bf, lw2, lb2, 0.f, t);    // loc2
  __syncthreads();
  pw_tile<128, 64, 1>(Bf, A, lw3, lb3, 0.f, t);     // loc3
  __syncthreads();

  {
    int pg = (t & 7) << 2;
    int og = t >> 3;  // NO = 3
    float acc[3][4];
#pragma unroll
    for (int j = 0; j < 3; ++j) {
      float bb = gb[og * 3 + j];
#pragma unroll
      for (int u = 0; u < 4; ++u) acc[j][u] = bb;
    }
    const float* cv = fc2o + b * 64;
#pragma unroll 4
    for (int k = 0; k < 64; k += 4) {
      float4 cc4 = *(const float4*)&cv[k];
      float4 xv0 = *(const float4*)&A[k][pg];
      float4 xv1 = *(const float4*)&A[k + 1][pg];
      float4 xv2 = *(const float4*)&A[k + 2][pg];
      float4 xv3 = *(const float4*)&A[k + 3][pg];
      xv0.x = fmaxf(xv0.x + cc4.x, 0.f); xv0.y = fmaxf(xv0.y + cc4.x, 0.f);
      xv0.z = fmaxf(xv0.z + cc4.x, 0.f); xv0.w = fmaxf(xv0.w + cc4.x, 0.f);
      xv1.x = fmaxf(xv1.x + cc4.y, 0.f); xv1.y = fmaxf(xv1.y + cc4.y, 0.f);
      xv1.z = fmaxf(xv1.z + cc4.y, 0.f); xv1.w = fmaxf(xv1.w + cc4.y, 0.f);
      xv2.x = fmaxf(xv2.x + cc4.z, 0.f); xv2.y = fmaxf(xv2.y + cc4.z, 0.f);
      xv2.z = fmaxf(xv2.z + cc4.z, 0.f); xv2.w = fmaxf(xv2.w + cc4.z, 0.f);
      xv3.x = fmaxf(xv3.x + cc4.w, 0.f); xv3.y = fmaxf(xv3.y + cc4.w, 0.f);
      xv3.z = fmaxf(xv3.z + cc4.w, 0.f); xv3.w = fmaxf(xv3.w + cc4.w, 0.f);
#pragma unroll
      for (int j = 0; j < 3; ++j) {
        float4 wv = *(const float4*)&gw[(og * 3 + j) * 64 + k];
        acc[j][0] += wv.x * xv0.x + wv.y * xv1.x + wv.z * xv2.x + wv.w * xv3.x;
        acc[j][1] += wv.x * xv0.y + wv.y * xv1.y + wv.z * xv2.y + wv.w * xv3.y;
        acc[j][2] += wv.x * xv0.z + wv.y * xv1.z + wv.z * xv2.z + wv.w * xv3.z;
        acc[j][3] += wv.x * xv0.w + wv.y * xv1.w + wv.z * xv2.w + wv.w * xv3.w;
      }
    }
#pragma unroll
    for (int j = 0; j < 3; ++j) {
      int o = og * 3 + j;
      int l = o / 12, cc = o - l * 12;
#pragma unroll
      for (int u = 0; u < 4; ++u)
        gridt[(size_t)(((b * 8 + l) << 8) + p0 + pg + u) * 12 + cc] = acc[j][u];
    }
  }
}

// ---------------- guide + bilateral slice + affine apply (fused, LDS grid) ----
#define ZST 200
__global__ __launch_bounds__(256) void slice_k(
    const float* __restrict__ img, const float* __restrict__ gridt,
    const float* __restrict__ ccm_w, const float* __restrict__ ccm_b,
    const float* __restrict__ shifts, const float* __restrict__ slopes,
    const float* __restrict__ prw, const float* __restrict__ prb,
    float* __restrict__ out) {
  int blk = blockIdx.x;          // BATCH*1024
  int b = blk >> 10;
  int h = blk & 1023;
  int t = threadIdx.x;

  __shared__ float sg[8 * ZST];      // 6400 B
  __shared__ float2 lut[3][16];      // CS, CB

  float cy = (h + 0.5f) * 0.015625f - 0.5f;
  float y0f = floorf(cy);
  float wy = cy - y0f;
  int y0 = (int)y0f;
  int yi0 = min(max(y0, 0), 15), yi1 = min(max(y0 + 1, 0), 15);

  if (t < 48) {  // build curve LUT (prefix sums over 16 knots)
    int c = t >> 4, k = t & 15;
    float cs = 0.f, cbv = 0.f;
    for (int i = 0; i <= k; ++i) {
      float s = slopes[c * 16 + i];
      cs += s;
      cbv += s * shifts[c * 16 + i];
    }
    lut[c][k] = make_float2(cs, cbv);
  }

  // stage y-lerped grid: 8 slabs x 48 float4
  for (int i = t; i < 384; i += 256) {
    int z = i / 48;
    int e = i - z * 48;
    const float4* s0 =
        (const float4*)(gridt + (size_t)(((b * 8 + z) << 8) + (yi0 << 4)) * 12);
    const float4* s1 =
        (const float4*)(gridt + (size_t)(((b * 8 + z) << 8) + (yi1 << 4)) * 12);
    float4 a = s0[e], c = s1[e];
    float4 v = make_float4(a.x + wy * (c.x - a.x), a.y + wy * (c.y - a.y),
                           a.z + wy * (c.z - a.z), a.w + wy * (c.w - a.w));
    *((float4*)(sg + z * ZST) + e) = v;
  }
  __syncthreads();

  int pp = (h << 10) + (t << 2);
  const float* ib = img + (size_t)b * 3 * HH * WW;
  float4 R4 = *(const float4*)(ib + pp);
  float4 G4 = *(const float4*)(ib + HH * WW + pp);
  float4 B4 = *(const float4*)(ib + 2 * HH * WW + pp);
  float r_[4] = {R4.x, R4.y, R4.z, R4.w};
  float g_[4] = {G4.x, G4.y, G4.z, G4.w};
  float b_[4] = {B4.x, B4.y, B4.z, B4.w};

  float m0 = ccm_w[0], m1 = ccm_w[1], m2 = ccm_w[2];
  float m3 = ccm_w[3], m4 = ccm_w[4], m5 = ccm_w[5];
  float m6 = ccm_w[6], m7 = ccm_w[7], m8 = ccm_w[8];
  float c0 = ccm_b[0], c1 = ccm_b[1], c2 = ccm_b[2];
  float p0 = prw[0], p1 = prw[1], p2 = prw[2], pb = prb[0];

  float base0 = shifts[0], base1 = shifts[16], base2 = shifts[32];
  float inv0 = 1.0f / (shifts[1] - base0);
  float inv1 = 1.0f / (shifts[17] - base1);
  float inv2 = 1.0f / (shifts[33] - base2);

  float ro[4], go[4], bo[4];
#pragma unroll
  for (int j = 0; j < 4; ++j) {
    float r = r_[j], g = g_[j], bl = b_[j];
    float v0 = c0 + m0 * r + m1 * g + m2 * bl;
    float v1 = c1 + m3 * r + m4 * g + m5 * bl;
    float v2 = c2 + m6 * r + m7 * g + m8 * bl;

    float tv0 = fmaxf(v0, base0);
    float tv1 = fmaxf(v1, base1);
    float tv2 = fmaxf(v2, base2);
    int j0 = min((int)((tv0 - base0) * inv0), 15);
    int j1 = min((int)((tv1 - base1) * inv1), 15);
    int j2 = min((int)((tv2 - base2) * inv2), 15);
    float2 e0 = lut[0][j0];
    float2 e1 = lut[1][j1];
    float2 e2 = lut[2][j2];
    float f0 = e0.x * tv0 - e0.y;
    float f1 = e1.x * tv1 - e1.y;
    float f2 = e2.x * tv2 - e2.y;

    float gg = pb + p0 * f0 + p1 * f1 + p2 * f2;
    float guide = fminf(fmaxf(gg, 0.f), 1.f);

    int w = (t << 2) + j;
    float cx = (w + 0.5f) * 0.015625f - 0.5f;
    float x0f = floorf(cx);
    float wx = cx - x0f;
    int x0i = (int)x0f;
    int xi0 = min(max(x0i, 0), 15), xi1 = min(max(x0i + 1, 0), 15);

    float cz = guide * 8.0f - 0.5f;
    float z0f = floorf(cz);
    float wz = cz - z0f;
    int z0i = (int)z0f;
    int zi0 = min(max(z0i, 0), 7), zi1 = min(max(z0i + 1, 0), 7);

    int oz0 = zi0 * ZST, oz1 = zi1 * ZST;
    int ox0 = xi0 * 12, ox1 = xi1 * 12;
    float wz1 = wz, wz0 = 1.f - wz;
    float wx1 = wx, wx0 = 1.f - wx;

    float acc[12];
#pragma unroll
    for (int k = 0; k < 12; ++k) acc[k] = 0.f;

#pragma unroll
    for (int dz = 0; dz < 2; ++dz) {
      int oz = dz ? oz1 : oz0;
      float wzz = dz ? wz1 : wz0;
#pragma unroll
      for (int dx = 0; dx < 2; ++dx) {
        int ox = dx ? ox1 : ox0;
        float wgt = wzz * (dx ? wx1 : wx0);
        const float* gp = sg + oz + ox;
        float4 a0 = *(const float4*)gp;
        float4 a1 = *(const float4*)(gp + 4);
        float4 a2 = *(const float4*)(gp + 8);
        acc[0] += wgt * a0.x;  acc[1] += wgt * a0.y;
        acc[2] += wgt * a0.z;  acc[3] += wgt * a0.w;
        acc[4] += wgt * a1.x;  acc[5] += wgt * a1.y;
        acc[6] += wgt * a1.z;  acc[7] += wgt * a1.w;
        acc[8] += wgt * a2.x;  acc[9] += wgt * a2.y;
        acc[10] += wgt * a2.z; acc[11] += wgt * a2.w;
      }
    }
    ro[j] = acc[0] * r + acc[1] * g + acc[2] * bl + acc[3];
    go[j] = acc[4] * r + acc[5] * g + acc[6] * bl + acc[7];
    bo[j] = acc[8] * r + acc[9] * g + acc[10] * bl + acc[11];
  }
  float* ob = out + (size_t)b * 3 * HH * WW;
  *(float4*)(ob + pp) = make_float4(ro[0], ro[1], ro[2], ro[3]);
  *(float4*)(ob + HH * WW + pp) = make_float4(go[0], go[1], go[2], go[3]);
  *(float4*)(ob + 2 * HH * WW + pp) = make_float4(bo[0], bo[1], bo[2], bo[3]);
}

extern "C" void kernel_launch(void* const* d_in, const int* in_sizes, int n_in,
                              void* d_out, int out_size, void* d_ws, size_t ws_size,
                              hipStream_t stream) {
  const float* image = (const float*)d_in[0];
  const float* val   = (const float*)d_in[1];
  const float* sw0 = (const float*)d_in[2];  const float* sb0 = (const float*)d_in[3];
  const float* sw1 = (const float*)d_in[4];  const float* sb1 = (const float*)d_in[5];
  const float* sw2 = (const float*)d_in[6];  const float* sb2 = (const float*)d_in[7];
  const float* sw3 = (const float*)d_in[8];  const float* sb3 = (const float*)d_in[9];
  const float* spw = (const float*)d_in[10]; const float* spb = (const float*)d_in[11];
  const float* lw1 = (const float*)d_in[12]; const float* lb1 = (const float*)d_in[13];
  const float* lw2 = (const float*)d_in[14]; const float* lb2 = (const float*)d_in[15];
  const float* lw3 = (const float*)d_in[16]; const float* lb3 = (const float*)d_in[17];
  const float* cw  = (const float*)d_in[18]; const float* cb  = (const float*)d_in[19];
  const float* fw1 = (const float*)d_in[20]; const float* fb1 = (const float*)d_in[21];
  const float* fw2 = (const float*)d_in[22]; const float* fb2 = (const float*)d_in[23];
  const float* gw  = (const float*)d_in[24]; const float* gb  = (const float*)d_in[25];
  const float* ccm_w = (const float*)d_in[26]; const float* ccm_b = (const float*)d_in[27];
  const float* shifts = (const float*)d_in[28]; const float* slopes = (const float*)d_in[29];
  const float* prw = (const float*)d_in[30]; const float* prb = (const float*)d_in[31];
  float* out = (float*)d_out;

  float* ws    = (float*)d_ws;
  float* x0    = ws;                  // 524288
  float* x1    = x0 + 524288;         // 262144
  float* x2    = x1 + 262144;         // 131072
  float* x3    = x2 + 131072;         // 65536
  float* fc2o  = x3 + 65536;          // 256
  float* gridt = fc2o + 256;          // 98304

  dsconv0_k<<<256, 256, 0, stream>>>(image, sw0, sb0, x0);
  conv_tile_k<8, 16, 128, 8><<<256, 256, 0, stream>>>(x0, sw1, sb1, x1);
  conv_tile_k<16, 32, 64, 4><<<256, 256, 0, stream>>>(x1, sw2, sb2, x2);
  conv_tile_k<32, 64, 32, 2><<<256, 256, 0, stream>>>(x2, sw3, sb3, x3);
  cpfc_k<<<1, 256, 0, stream>>>(x3, spw, spb, val, cw, cb, fw1, fb1, fw2, fb2,
                                fc2o);
  mlp_k<<<32, 256, 0, stream>>>(x3, spw, spb, val, lw1, lb1, lw2, lb2, lw3, lb3,
                                fc2o, gw, gb, gridt);
  slice_k<<<4096, 256, 0, stream>>>(image, gridt, ccm_w, ccm_b, shifts, slopes,
                                    prw, prb, out);
}

// Round 9
// 246.033 us; speedup vs baseline: 1.4220x; 1.1245x over previous
//
#include <hip/hip_runtime.h>

#define BATCH 4
#define HH 1024
#define WW 1024

// ---------------- fused downsample(1024->256) + conv0 (3->8, s2, relu) -------
__global__ __launch_bounds__(256) void dsconv0_k(const float* __restrict__ img,
                                                 const float* __restrict__ wgt,
                                                 const float* __restrict__ bias,
                                                 float* __restrict__ out) {
  int blk = blockIdx.x;            // b*64 + ty*8 + tx
  int tx = blk & 7;
  int ty = (blk >> 3) & 7;
  int b = blk >> 6;
  int t = threadIdx.x;

  __shared__ float low[3][33][36];  // padded row stride 36

  int Y0 = ty << 4, X0 = tx << 4;  // output tile origin (128x128 space)
  int gy0 = 2 * Y0 - 1, gx0 = 2 * X0 - 1;  // low-res support origin

  for (int i = t; i < 3 * 33 * 33; i += 256) {
    int c = i / 1089;
    int rem = i - c * 1089;
    int ly = rem / 33;
    int lx = rem - ly * 33;
    int gy = gy0 + ly, gx = gx0 + lx;
    float v = 0.f;
    if (gy >= 0 && gx >= 0) {
      const float* p = img + (size_t)(b * 3 + c) * HH * WW + (4 * gy + 1) * WW + 4 * gx + 1;
      v = 0.25f * (p[0] + p[1] + p[WW] + p[WW + 1]);
    }
    low[c][ly][lx] = v;
  }
  __syncthreads();

  int x = t & 15, y = t >> 4;
  float acc[8];
#pragma unroll
  for (int o = 0; o < 8; ++o) acc[o] = bias[o];
  for (int ci = 0; ci < 3; ++ci) {
#pragma unroll
    for (int ky = 0; ky < 3; ++ky) {
#pragma unroll
      for (int kx = 0; kx < 3; ++kx) {
        float v = low[ci][2 * y + ky][2 * x + kx];
#pragma unroll
        for (int o = 0; o < 8; ++o)
          acc[o] += wgt[o * 27 + ci * 9 + ky * 3 + kx] * v;
      }
    }
  }
  float* ob = out + (size_t)b * 8 * 128 * 128 + (Y0 + y) * 128 + X0 + x;
#pragma unroll
  for (int o = 0; o < 8; ++o) ob[o * 128 * 128] = fmaxf(acc[o], 0.f);
}

// ---------------- LDS-tiled 3x3 s2 conv, PxP output tile ---------------------
// Blocks = BATCH * (HO/P)^2; choose P so that's >= 256 (latency hiding!).
template <int CI, int CO, int HI, int P>
__global__ __launch_bounds__(256) void conv_tile_k(const float* __restrict__ in,
                                                   const float* __restrict__ wgt,
                                                   const float* __restrict__ bias,
                                                   float* __restrict__ out) {
  const int HO = HI / 2;
  const int NT = HO / P;
  const int HALO = 2 * P + 1;
  const int RS = 2 * P + 4;       // padded row stride
  constexpr int NO = (CO * P * P) / 256;
  int blk = blockIdx.x;
  int tx = blk % NT;
  int ty = (blk / NT) % NT;
  int b = blk / (NT * NT);
  int t = threadIdx.x;

  __shared__ float s[CI][HALO][RS];

  int Y0 = ty * P, X0 = tx * P;
  int gy0 = 2 * Y0 - 1, gx0 = 2 * X0 - 1;

  for (int i = t; i < CI * HALO * HALO; i += 256) {
    int c = i / (HALO * HALO);
    int rem = i - c * (HALO * HALO);
    int ly = rem / HALO;
    int lx = rem - ly * HALO;
    int gy = gy0 + ly, gx = gx0 + lx;
    float v = 0.f;
    if (gy >= 0 && gy < HI && gx >= 0 && gx < HI)
      v = in[((size_t)(b * CI + c) * HI + gy) * HI + gx];
    s[c][ly][lx] = v;
  }
  __syncthreads();

  int px = t % (P * P);
  int og = t / (P * P);
  int x = px % P, y = px / P;
  float acc[NO];
#pragma unroll
  for (int j = 0; j < NO; ++j) acc[j] = bias[og * NO + j];
  for (int ci = 0; ci < CI; ++ci) {
#pragma unroll
    for (int ky = 0; ky < 3; ++ky) {
#pragma unroll
      for (int kx = 0; kx < 3; ++kx) {
        float v = s[ci][2 * y + ky][2 * x + kx];
#pragma unroll
        for (int j = 0; j < NO; ++j)
          acc[j] += wgt[((og * NO + j) * CI + ci) * 9 + ky * 3 + kx] * v;
      }
    }
  }
#pragma unroll
  for (int j = 0; j < NO; ++j)
    out[(size_t)(b * CO + og * NO + j) * HO * HO + (Y0 + y) * HO + X0 + x] =
        fmaxf(acc[j], 0.f);
}

// ---------------- global path: composed splat + cpool -> cvec (16 blocks) -----
// One block per (b, ch). c_pre[ch](p) = eb + sum_k eff[k]*x3[b,k,p], with
// eff[k] = sum_o cw[ch,o]*spw[o,k] (splat has no relu -> exact composition).
// Then relu, 2x2 mean pool over the 8x8 of ::2,::2 positions -> cvec[b*64+ch*16+i].
__global__ __launch_bounds__(256) void cpool_k(const float* __restrict__ x3,
                                               const float* __restrict__ spw,
                                               const float* __restrict__ spb,
                                               const float* __restrict__ val,
                                               const float* __restrict__ cw,
                                               const float* __restrict__ cb,
                                               float* __restrict__ cvec) {
  int blk = blockIdx.x;  // b*4 + ch
  int ch = blk & 3, b = blk >> 2;
  int t = threadIdx.x;
  int k = t & 63, q = t >> 6;  // q in 0..3

  __shared__ float red[4][64];
  __shared__ float red2[4];
  __shared__ float effs[64];
  __shared__ float s8[64];
  __shared__ float ebs;

  {  // eff[k] partials over o-quarters
    float a = 0.f;
#pragma unroll
    for (int o = q * 16; o < q * 16 + 16; ++o)
      a += cw[ch * 64 + o] * spw[o * 64 + k];
    red[q][k] = a;
  }
  if (k == 0) {  // eb partials
    float a = 0.f;
    float vb = val[b];
#pragma unroll
    for (int o = q * 16; o < q * 16 + 16; ++o)
      a += cw[ch * 64 + o] * (spb[o] + vb);
    red2[q] = a;
  }
  __syncthreads();
  if (t < 64) effs[t] = red[0][t] + red[1][t] + red[2][t] + red[3][t];
  if (t == 0) ebs = cb[ch] + red2[0] + red2[1] + red2[2] + red2[3];
  __syncthreads();

  {  // position i = k: yy=i>>3, xx=i&7 -> raw p = yy*32 + xx*2
    int p = ((k >> 3) << 5) + ((k & 7) << 1);
    float a = 0.f;
#pragma unroll
    for (int kk = q * 16; kk < q * 16 + 16; ++kk)
      a += effs[kk] * x3[((size_t)(b * 64 + kk)) * 256 + p];
    red[q][k] = a;
  }
  __syncthreads();
  if (t < 64)
    s8[t] = fmaxf(red[0][t] + red[1][t] + red[2][t] + red[3][t] + ebs, 0.f);
  __syncthreads();
  if (t < 16) {
    int py = t >> 2, px = t & 3;
    int i0 = (py * 2) * 8 + px * 2;
    cvec[b * 64 + ch * 16 + t] =
        0.25f * (s8[i0] + s8[i0 + 1] + s8[i0 + 8] + s8[i0 + 9]);
  }
}

// ---------------- fused pointwise chain: splat->loc1->loc2->loc3->coeff -------
// (+ the two 64x64 FC layers computed redundantly per block from cvec,
//  overlapped with the pw_tile phases -> no extra syncs, no fc kernel.)
template <int CI, int CO, int RELU>
__device__ __forceinline__ void pw_tile(const float (*__restrict__ X)[36],
                                        float (*__restrict__ Y)[36],
                                        const float* __restrict__ w,
                                        const float* __restrict__ bias,
                                        float badd, int t) {
  constexpr int NO = CO / 32;
  int pg = (t & 7) << 2;
  int og = t >> 3;
  float acc[NO][4];
#pragma unroll
  for (int j = 0; j < NO; ++j) {
    float bb = bias[og * NO + j] + badd;
#pragma unroll
    for (int u = 0; u < 4; ++u) acc[j][u] = bb;
  }
#pragma unroll 4
  for (int k = 0; k < CI; k += 4) {
    float4 xv0 = *(const float4*)&X[k][pg];
    float4 xv1 = *(const float4*)&X[k + 1][pg];
    float4 xv2 = *(const float4*)&X[k + 2][pg];
    float4 xv3 = *(const float4*)&X[k + 3][pg];
#pragma unroll
    for (int j = 0; j < NO; ++j) {
      float4 wv = *(const float4*)&w[(og * NO + j) * CI + k];
      acc[j][0] += wv.x * xv0.x + wv.y * xv1.x + wv.z * xv2.x + wv.w * xv3.x;
      acc[j][1] += wv.x * xv0.y + wv.y * xv1.y + wv.z * xv2.y + wv.w * xv3.y;
      acc[j][2] += wv.x * xv0.z + wv.y * xv1.z + wv.z * xv2.z + wv.w * xv3.z;
      acc[j][3] += wv.x * xv0.w + wv.y * xv1.w + wv.z * xv2.w + wv.w * xv3.w;
    }
  }
#pragma unroll
  for (int j = 0; j < NO; ++j) {
    int o = og * NO + j;
#pragma unroll
    for (int u = 0; u < 4; ++u) {
      float v = acc[j][u];
      if (RELU) v = fmaxf(v, 0.f);
      Y[o][pg + u] = v;
    }
  }
}

__global__ __launch_bounds__(256) void mlp_k(
    const float* __restrict__ x3, const float* __restrict__ spw,
    const float* __restrict__ spb, const float* __restrict__ val,
    const float* __restrict__ lw1, const float* __restrict__ lb1,
    const float* __restrict__ lw2, const float* __restrict__ lb2,
    const float* __restrict__ lw3, const float* __restrict__ lb3,
    const float* __restrict__ cvec, const float* __restrict__ fw1,
    const float* __restrict__ fb1, const float* __restrict__ fw2,
    const float* __restrict__ fb2, const float* __restrict__ gw,
    const float* __restrict__ gb, float* __restrict__ gridt) {
  int blk = blockIdx.x;  // b*8 + pg
  int b = blk >> 3;
  int p0 = (blk & 7) << 5;
  int t = threadIdx.x;

  __shared__ float A[128][36];
  __shared__ float Bf[128][36];
  __shared__ float scv[64], h1v[64], f2v[64];

  if (t < 64) scv[t] = cvec[b * 64 + t];
  for (int i = t; i < 64 * 32; i += 256) {
    int c = i >> 5, p = i & 31;
    A[c][p] = x3[((size_t)(b * 64 + c)) * 256 + p0 + p];
  }
  __syncthreads();

  if (t < 64) {  // FC1 (overlapped with splat phase)
    float a = fb1[t];
#pragma unroll 8
    for (int k = 0; k < 64; ++k) a += fw1[t * 64 + k] * scv[k];
    h1v[t] = fmaxf(a, 0.f);
  }
  pw_tile<64, 64, 0>(A, Bf, spw, spb, val[b], t);   // splat (no relu)
  __syncthreads();
  if (t < 64) {  // FC2 (overlapped with loc1 phase)
    float a = fb2[t];
#pragma unroll 8
    for (int k = 0; k < 64; ++k) a += fw2[t * 64 + k] * h1v[k];
    f2v[t] = fmaxf(a, 0.f);
  }
  pw_tile<64, 128, 1>(Bf, A, lw1, lb1, 0.f, t);     // loc1
  __syncthreads();
  pw_tile<128, 128, 1>(A, Bf, lw2, lb2, 0.f, t);    // loc2
  __syncthreads();
  pw_tile<128, 64, 1>(Bf, A, lw3, lb3, 0.f, t);     // loc3
  __syncthreads();

  {
    int pg = (t & 7) << 2;
    int og = t >> 3;  // NO = 3
    float acc[3][4];
#pragma unroll
    for (int j = 0; j < 3; ++j) {
      float bb = gb[og * 3 + j];
#pragma unroll
      for (int u = 0; u < 4; ++u) acc[j][u] = bb;
    }
#pragma unroll 4
    for (int k = 0; k < 64; k += 4) {
      float4 cc4 = *(const float4*)&f2v[k];
      float4 xv0 = *(const float4*)&A[k][pg];
      float4 xv1 = *(const float4*)&A[k + 1][pg];
      float4 xv2 = *(const float4*)&A[k + 2][pg];
      float4 xv3 = *(const float4*)&A[k + 3][pg];
      xv0.x = fmaxf(xv0.x + cc4.x, 0.f); xv0.y = fmaxf(xv0.y + cc4.x, 0.f);
      xv0.z = fmaxf(xv0.z + cc4.x, 0.f); xv0.w = fmaxf(xv0.w + cc4.x, 0.f);
      xv1.x = fmaxf(xv1.x + cc4.y, 0.f); xv1.y = fmaxf(xv1.y + cc4.y, 0.f);
      xv1.z = fmaxf(xv1.z + cc4.y, 0.f); xv1.w = fmaxf(xv1.w + cc4.y, 0.f);
      xv2.x = fmaxf(xv2.x + cc4.z, 0.f); xv2.y = fmaxf(xv2.y + cc4.z, 0.f);
      xv2.z = fmaxf(xv2.z + cc4.z, 0.f); xv2.w = fmaxf(xv2.w + cc4.z, 0.f);
      xv3.x = fmaxf(xv3.x + cc4.w, 0.f); xv3.y = fmaxf(xv3.y + cc4.w, 0.f);
      xv3.z = fmaxf(xv3.z + cc4.w, 0.f); xv3.w = fmaxf(xv3.w + cc4.w, 0.f);
#pragma unroll
      for (int j = 0; j < 3; ++j) {
        float4 wv = *(const float4*)&gw[(og * 3 + j) * 64 + k];
        acc[j][0] += wv.x * xv0.x + wv.y * xv1.x + wv.z * xv2.x + wv.w * xv3.x;
        acc[j][1] += wv.x * xv0.y + wv.y * xv1.y + wv.z * xv2.y + wv.w * xv3.y;
        acc[j][2] += wv.x * xv0.z + wv.y * xv1.z + wv.z * xv2.z + wv.w * xv3.z;
        acc[j][3] += wv.x * xv0.w + wv.y * xv1.w + wv.z * xv2.w + wv.w * xv3.w;
      }
    }
#pragma unroll
    for (int j = 0; j < 3; ++j) {
      int o = og * 3 + j;
      int l = o / 12, cc = o - l * 12;
#pragma unroll
      for (int u = 0; u < 4; ++u)
        gridt[(size_t)(((b * 8 + l) << 8) + p0 + pg + u) * 12 + cc] = acc[j][u];
    }
  }
}

// ---------------- guide + bilateral slice + affine apply (fused, LDS grid) ----
#define ZST 200
__global__ __launch_bounds__(256) void slice_k(
    const float* __restrict__ img, const float* __restrict__ gridt,
    const float* __restrict__ ccm_w, const float* __restrict__ ccm_b,
    const float* __restrict__ shifts, const float* __restrict__ slopes,
    const float* __restrict__ prw, const float* __restrict__ prb,
    float* __restrict__ out) {
  int blk = blockIdx.x;          // BATCH*1024
  int b = blk >> 10;
  int h = blk & 1023;
  int t = threadIdx.x;

  __shared__ float sg[8 * ZST];      // 6400 B
  __shared__ float2 lut[3][16];      // CS, CB

  float cy = (h + 0.5f) * 0.015625f - 0.5f;
  float y0f = floorf(cy);
  float wy = cy - y0f;
  int y0 = (int)y0f;
  int yi0 = min(max(y0, 0), 15), yi1 = min(max(y0 + 1, 0), 15);

  if (t < 48) {  // build curve LUT (prefix sums over 16 knots)
    int c = t >> 4, k = t & 15;
    float cs = 0.f, cbv = 0.f;
    for (int i = 0; i <= k; ++i) {
      float s = slopes[c * 16 + i];
      cs += s;
      cbv += s * shifts[c * 16 + i];
    }
    lut[c][k] = make_float2(cs, cbv);
  }

  // stage y-lerped grid: 8 slabs x 48 float4
  for (int i = t; i < 384; i += 256) {
    int z = i / 48;
    int e = i - z * 48;
    const float4* s0 =
        (const float4*)(gridt + (size_t)(((b * 8 + z) << 8) + (yi0 << 4)) * 12);
    const float4* s1 =
        (const float4*)(gridt + (size_t)(((b * 8 + z) << 8) + (yi1 << 4)) * 12);
    float4 a = s0[e], c = s1[e];
    float4 v = make_float4(a.x + wy * (c.x - a.x), a.y + wy * (c.y - a.y),
                           a.z + wy * (c.z - a.z), a.w + wy * (c.w - a.w));
    *((float4*)(sg + z * ZST) + e) = v;
  }
  __syncthreads();

  int pp = (h << 10) + (t << 2);
  const float* ib = img + (size_t)b * 3 * HH * WW;
  float4 R4 = *(const float4*)(ib + pp);
  float4 G4 = *(const float4*)(ib + HH * WW + pp);
  float4 B4 = *(const float4*)(ib + 2 * HH * WW + pp);
  float r_[4] = {R4.x, R4.y, R4.z, R4.w};
  float g_[4] = {G4.x, G4.y, G4.z, G4.w};
  float b_[4] = {B4.x, B4.y, B4.z, B4.w};

  float m0 = ccm_w[0], m1 = ccm_w[1], m2 = ccm_w[2];
  float m3 = ccm_w[3], m4 = ccm_w[4], m5 = ccm_w[5];
  float m6 = ccm_w[6], m7 = ccm_w[7], m8 = ccm_w[8];
  float c0 = ccm_b[0], c1 = ccm_b[1], c2 = ccm_b[2];
  float p0 = prw[0], p1 = prw[1], p2 = prw[2], pb = prb[0];

  float base0 = shifts[0], base1 = shifts[16], base2 = shifts[32];
  float inv0 = 1.0f / (shifts[1] - base0);
  float inv1 = 1.0f / (shifts[17] - base1);
  float inv2 = 1.0f / (shifts[33] - base2);

  float ro[4], go[4], bo[4];
#pragma unroll
  for (int j = 0; j < 4; ++j) {
    float r = r_[j], g = g_[j], bl = b_[j];
    float v0 = c0 + m0 * r + m1 * g + m2 * bl;
    float v1 = c1 + m3 * r + m4 * g + m5 * bl;
    float v2 = c2 + m6 * r + m7 * g + m8 * bl;

    float tv0 = fmaxf(v0, base0);
    float tv1 = fmaxf(v1, base1);
    float tv2 = fmaxf(v2, base2);
    int j0 = min((int)((tv0 - base0) * inv0), 15);
    int j1 = min((int)((tv1 - base1) * inv1), 15);
    int j2 = min((int)((tv2 - base2) * inv2), 15);
    float2 e0 = lut[0][j0];
    float2 e1 = lut[1][j1];
    float2 e2 = lut[2][j2];
    float f0 = e0.x * tv0 - e0.y;
    float f1 = e1.x * tv1 - e1.y;
    float f2 = e2.x * tv2 - e2.y;

    float gg = pb + p0 * f0 + p1 * f1 + p2 * f2;
    float guide = fminf(fmaxf(gg, 0.f), 1.f);

    int w = (t << 2) + j;
    float cx = (w + 0.5f) * 0.015625f - 0.5f;
    float x0f = floorf(cx);
    float wx = cx - x0f;
    int x0i = (int)x0f;
    int xi0 = min(max(x0i, 0), 15), xi1 = min(max(x0i + 1, 0), 15);

    float cz = guide * 8.0f - 0.5f;
    float z0f = floorf(cz);
    float wz = cz - z0f;
    int z0i = (int)z0f;
    int zi0 = min(max(z0i, 0), 7), zi1 = min(max(z0i + 1, 0), 7);

    int oz0 = zi0 * ZST, oz1 = zi1 * ZST;
    int ox0 = xi0 * 12, ox1 = xi1 * 12;
    float wz1 = wz, wz0 = 1.f - wz;
    float wx1 = wx, wx0 = 1.f - wx;

    float acc[12];
#pragma unroll
    for (int k = 0; k < 12; ++k) acc[k] = 0.f;

#pragma unroll
    for (int dz = 0; dz < 2; ++dz) {
      int oz = dz ? oz1 : oz0;
      float wzz = dz ? wz1 : wz0;
#pragma unroll
      for (int dx = 0; dx < 2; ++dx) {
        int ox = dx ? ox1 : ox0;
        float wgt = wzz * (dx ? wx1 : wx0);
        const float* gp = sg + oz + ox;
        float4 a0 = *(const float4*)gp;
        float4 a1 = *(const float4*)(gp + 4);
        float4 a2 = *(const float4*)(gp + 8);
        acc[0] += wgt * a0.x;  acc[1] += wgt * a0.y;
        acc[2] += wgt * a0.z;  acc[3] += wgt * a0.w;
        acc[4] += wgt * a1.x;  acc[5] += wgt * a1.y;
        acc[6] += wgt * a1.z;  acc[7] += wgt * a1.w;
        acc[8] += wgt * a2.x;  acc[9] += wgt * a2.y;
        acc[10] += wgt * a2.z; acc[11] += wgt * a2.w;
      }
    }
    ro[j] = acc[0] * r + acc[1] * g + acc[2] * bl + acc[3];
    go[j] = acc[4] * r + acc[5] * g + acc[6] * bl + acc[7];
    bo[j] = acc[8] * r + acc[9] * g + acc[10] * bl + acc[11];
  }
  float* ob = out + (size_t)b * 3 * HH * WW;
  *(float4*)(ob + pp) = make_float4(ro[0], ro[1], ro[2], ro[3]);
  *(float4*)(ob + HH * WW + pp) = make_float4(go[0], go[1], go[2], go[3]);
  *(float4*)(ob + 2 * HH * WW + pp) = make_float4(bo[0], bo[1], bo[2], bo[3]);
}

extern "C" void kernel_launch(void* const* d_in, const int* in_sizes, int n_in,
                              void* d_out, int out_size, void* d_ws, size_t ws_size,
                              hipStream_t stream) {
  const float* image = (const float*)d_in[0];
  const float* val   = (const float*)d_in[1];
  const float* sw0 = (const float*)d_in[2];  const float* sb0 = (const float*)d_in[3];
  const float* sw1 = (const float*)d_in[4];  const float* sb1 = (const float*)d_in[5];
  const float* sw2 = (const float*)d_in[6];  const float* sb2 = (const float*)d_in[7];
  const float* sw3 = (const float*)d_in[8];  const float* sb3 = (const float*)d_in[9];
  const float* spw = (const float*)d_in[10]; const float* spb = (const float*)d_in[11];
  const float* lw1 = (const float*)d_in[12]; const float* lb1 = (const float*)d_in[13];
  const float* lw2 = (const float*)d_in[14]; const float* lb2 = (const float*)d_in[15];
  const float* lw3 = (const float*)d_in[16]; const float* lb3 = (const float*)d_in[17];
  const float* cw  = (const float*)d_in[18]; const float* cb  = (const float*)d_in[19];
  const float* fw1 = (const float*)d_in[20]; const float* fb1 = (const float*)d_in[21];
  const float* fw2 = (const float*)d_in[22]; const float* fb2 = (const float*)d_in[23];
  const float* gw  = (const float*)d_in[24]; const float* gb  = (const float*)d_in[25];
  const float* ccm_w = (const float*)d_in[26]; const float* ccm_b = (const float*)d_in[27];
  const float* shifts = (const float*)d_in[28]; const float* slopes = (const float*)d_in[29];
  const float* prw = (const float*)d_in[30]; const float* prb = (const float*)d_in[31];
  float* out = (float*)d_out;

  float* ws    = (float*)d_ws;
  float* x0    = ws;                  // 524288
  float* x1    = x0 + 524288;         // 262144
  float* x2    = x1 + 262144;         // 131072
  float* x3    = x2 + 131072;         // 65536
  float* cvec  = x3 + 65536;          // 256
  float* gridt = cvec + 256;          // 98304

  dsconv0_k<<<256, 256, 0, stream>>>(image, sw0, sb0, x0);
  conv_tile_k<8, 16, 128, 8><<<256, 256, 0, stream>>>(x0, sw1, sb1, x1);
  conv_tile_k<16, 32, 64, 4><<<256, 256, 0, stream>>>(x1, sw2, sb2, x2);
  conv_tile_k<32, 64, 32, 2><<<256, 256, 0, stream>>>(x2, sw3, sb3, x3);
  cpool_k<<<16, 256, 0, stream>>>(x3, spw, spb, val, cw, cb, cvec);
  mlp_k<<<32, 256, 0, stream>>>(x3, spw, spb, val, lw1, lb1, lw2, lb2, lw3, lb3,
                                cvec, fw1, fb1, fw2, fb2, gw, gb, gridt);
  slice_k<<<4096, 256, 0, stream>>>(image, gridt, ccm_w, ccm_b, shifts, slopes,
                                    prw, prb, out);
}

// Round 10
// 243.369 us; speedup vs baseline: 1.4376x; 1.0109x over previous
//
#include <hip/hip_runtime.h>

#define BATCH 4
#define HH 1024
#define WW 1024

// ---------------- fused downsample(1024->256) + conv0 (3->8, s2, relu) -------
__global__ __launch_bounds__(256) void dsconv0_k(const float* __restrict__ img,
                                                 const float* __restrict__ wgt,
                                                 const float* __restrict__ bias,
                                                 float* __restrict__ out) {
  int blk = blockIdx.x;            // b*64 + ty*8 + tx
  int tx = blk & 7;
  int ty = (blk >> 3) & 7;
  int b = blk >> 6;
  int t = threadIdx.x;

  __shared__ float low[3][33][36];  // padded row stride 36

  int Y0 = ty << 4, X0 = tx << 4;  // output tile origin (128x128 space)
  int gy0 = 2 * Y0 - 1, gx0 = 2 * X0 - 1;  // low-res support origin

  for (int i = t; i < 3 * 33 * 33; i += 256) {
    int c = i / 1089;
    int rem = i - c * 1089;
    int ly = rem / 33;
    int lx = rem - ly * 33;
    int gy = gy0 + ly, gx = gx0 + lx;
    float v = 0.f;
    if (gy >= 0 && gx >= 0) {
      const float* p = img + (size_t)(b * 3 + c) * HH * WW + (4 * gy + 1) * WW + 4 * gx + 1;
      float2 u0 = *(const float2*)p;
      float2 u1 = *(const float2*)(p + WW);
      v = 0.25f * (u0.x + u0.y + u1.x + u1.y);
    }
    low[c][ly][lx] = v;
  }
  __syncthreads();

  int x = t & 15, y = t >> 4;
  float acc[8];
#pragma unroll
  for (int o = 0; o < 8; ++o) acc[o] = bias[o];
  for (int ci = 0; ci < 3; ++ci) {
#pragma unroll
    for (int ky = 0; ky < 3; ++ky) {
#pragma unroll
      for (int kx = 0; kx < 3; ++kx) {
        float v = low[ci][2 * y + ky][2 * x + kx];
#pragma unroll
        for (int o = 0; o < 8; ++o)
          acc[o] += wgt[o * 27 + ci * 9 + ky * 3 + kx] * v;
      }
    }
  }
  float* ob = out + (size_t)b * 8 * 128 * 128 + (Y0 + y) * 128 + X0 + x;
#pragma unroll
  for (int o = 0; o < 8; ++o) ob[o * 128 * 128] = fmaxf(acc[o], 0.f);
}

// ---------------- LDS-tiled 3x3 s2 conv, PxP output tile ---------------------
// Blocks = BATCH * (HO/P)^2; choose P so that's >= 256 (latency hiding!).
template <int CI, int CO, int HI, int P>
__global__ __launch_bounds__(256) void conv_tile_k(const float* __restrict__ in,
                                                   const float* __restrict__ wgt,
                                                   const float* __restrict__ bias,
                                                   float* __restrict__ out) {
  const int HO = HI / 2;
  const int NT = HO / P;
  const int HALO = 2 * P + 1;
  const int RS = 2 * P + 4;       // padded row stride
  constexpr int NO = (CO * P * P) / 256;
  int blk = blockIdx.x;
  int tx = blk % NT;
  int ty = (blk / NT) % NT;
  int b = blk / (NT * NT);
  int t = threadIdx.x;

  __shared__ float s[CI][HALO][RS];

  int Y0 = ty * P, X0 = tx * P;
  int gy0 = 2 * Y0 - 1, gx0 = 2 * X0 - 1;

  for (int i = t; i < CI * HALO * HALO; i += 256) {
    int c = i / (HALO * HALO);
    int rem = i - c * (HALO * HALO);
    int ly = rem / HALO;
    int lx = rem - ly * HALO;
    int gy = gy0 + ly, gx = gx0 + lx;
    float v = 0.f;
    if (gy >= 0 && gy < HI && gx >= 0 && gx < HI)
      v = in[((size_t)(b * CI + c) * HI + gy) * HI + gx];
    s[c][ly][lx] = v;
  }
  __syncthreads();

  int px = t % (P * P);
  int og = t / (P * P);
  int x = px % P, y = px / P;
  float acc[NO];
#pragma unroll
  for (int j = 0; j < NO; ++j) acc[j] = bias[og * NO + j];
  for (int ci = 0; ci < CI; ++ci) {
#pragma unroll
    for (int ky = 0; ky < 3; ++ky) {
#pragma unroll
      for (int kx = 0; kx < 3; ++kx) {
        float v = s[ci][2 * y + ky][2 * x + kx];
#pragma unroll
        for (int j = 0; j < NO; ++j)
          acc[j] += wgt[((og * NO + j) * CI + ci) * 9 + ky * 3 + kx] * v;
      }
    }
  }
#pragma unroll
  for (int j = 0; j < NO; ++j)
    out[(size_t)(b * CO + og * NO + j) * HO * HO + (Y0 + y) * HO + X0 + x] =
        fmaxf(acc[j], 0.f);
}

// ---------------- global path: composed splat + cpool -> cvec (16 blocks) -----
__global__ __launch_bounds__(256) void cpool_k(const float* __restrict__ x3,
                                               const float* __restrict__ spw,
                                               const float* __restrict__ spb,
                                               const float* __restrict__ val,
                                               const float* __restrict__ cw,
                                               const float* __restrict__ cb,
                                               float* __restrict__ cvec) {
  int blk = blockIdx.x;  // b*4 + ch
  int ch = blk & 3, b = blk >> 2;
  int t = threadIdx.x;
  int k = t & 63, q = t >> 6;  // q in 0..3

  __shared__ float red[4][64];
  __shared__ float red2[4];
  __shared__ float effs[64];
  __shared__ float s8[64];
  __shared__ float ebs;

  {  // eff[k] partials over o-quarters
    float a = 0.f;
#pragma unroll
    for (int o = q * 16; o < q * 16 + 16; ++o)
      a += cw[ch * 64 + o] * spw[o * 64 + k];
    red[q][k] = a;
  }
  if (k == 0) {  // eb partials
    float a = 0.f;
    float vb = val[b];
#pragma unroll
    for (int o = q * 16; o < q * 16 + 16; ++o)
      a += cw[ch * 64 + o] * (spb[o] + vb);
    red2[q] = a;
  }
  __syncthreads();
  if (t < 64) effs[t] = red[0][t] + red[1][t] + red[2][t] + red[3][t];
  if (t == 0) ebs = cb[ch] + red2[0] + red2[1] + red2[2] + red2[3];
  __syncthreads();

  {  // position i = k: yy=i>>3, xx=i&7 -> raw p = yy*32 + xx*2
    int p = ((k >> 3) << 5) + ((k & 7) << 1);
    float a = 0.f;
#pragma unroll
    for (int kk = q * 16; kk < q * 16 + 16; ++kk)
      a += effs[kk] * x3[((size_t)(b * 64 + kk)) * 256 + p];
    red[q][k] = a;
  }
  __syncthreads();
  if (t < 64)
    s8[t] = fmaxf(red[0][t] + red[1][t] + red[2][t] + red[3][t] + ebs, 0.f);
  __syncthreads();
  if (t < 16) {
    int py = t >> 2, px = t & 3;
    int i0 = (py * 2) * 8 + px * 2;
    cvec[b * 64 + ch * 16 + t] =
        0.25f * (s8[i0] + s8[i0 + 1] + s8[i0 + 8] + s8[i0 + 9]);
  }
}

// ---------------- fused pointwise chain: splat->loc1->loc2->loc3->coeff -------
template <int CI, int CO, int RELU>
__device__ __forceinline__ void pw_tile(const float (*__restrict__ X)[36],
                                        float (*__restrict__ Y)[36],
                                        const float* __restrict__ w,
                                        const float* __restrict__ bias,
                                        float badd, int t) {
  constexpr int NO = CO / 32;
  int pg = (t & 7) << 2;
  int og = t >> 3;
  float acc[NO][4];
#pragma unroll
  for (int j = 0; j < NO; ++j) {
    float bb = bias[og * NO + j] + badd;
#pragma unroll
    for (int u = 0; u < 4; ++u) acc[j][u] = bb;
  }
#pragma unroll 4
  for (int k = 0; k < CI; k += 4) {
    float4 xv0 = *(const float4*)&X[k][pg];
    float4 xv1 = *(const float4*)&X[k + 1][pg];
    float4 xv2 = *(const float4*)&X[k + 2][pg];
    float4 xv3 = *(const float4*)&X[k + 3][pg];
#pragma unroll
    for (int j = 0; j < NO; ++j) {
      float4 wv = *(const float4*)&w[(og * NO + j) * CI + k];
      acc[j][0] += wv.x * xv0.x + wv.y * xv1.x + wv.z * xv2.x + wv.w * xv3.x;
      acc[j][1] += wv.x * xv0.y + wv.y * xv1.y + wv.z * xv2.y + wv.w * xv3.y;
      acc[j][2] += wv.x * xv0.z + wv.y * xv1.z + wv.z * xv2.z + wv.w * xv3.z;
      acc[j][3] += wv.x * xv0.w + wv.y * xv1.w + wv.z * xv2.w + wv.w * xv3.w;
    }
  }
#pragma unroll
  for (int j = 0; j < NO; ++j) {
    int o = og * NO + j;
#pragma unroll
    for (int u = 0; u < 4; ++u) {
      float v = acc[j][u];
      if (RELU) v = fmaxf(v, 0.f);
      Y[o][pg + u] = v;
    }
  }
}

__global__ __launch_bounds__(256) void mlp_k(
    const float* __restrict__ x3, const float* __restrict__ spw,
    const float* __restrict__ spb, const float* __restrict__ val,
    const float* __restrict__ lw1, const float* __restrict__ lb1,
    const float* __restrict__ lw2, const float* __restrict__ lb2,
    const float* __restrict__ lw3, const float* __restrict__ lb3,
    const float* __restrict__ cvec, const float* __restrict__ fw1,
    const float* __restrict__ fb1, const float* __restrict__ fw2,
    const float* __restrict__ fb2, const float* __restrict__ gw,
    const float* __restrict__ gb, float* __restrict__ gridt) {
  int blk = blockIdx.x;  // b*8 + pg
  int b = blk >> 3;
  int p0 = (blk & 7) << 5;
  int t = threadIdx.x;

  __shared__ float A[128][36];
  __shared__ float Bf[128][36];
  __shared__ float scv[64], h1v[64], f2v[64];

  if (t < 64) scv[t] = cvec[b * 64 + t];
  for (int i = t; i < 64 * 32; i += 256) {
    int c = i >> 5, p = i & 31;
    A[c][p] = x3[((size_t)(b * 64 + c)) * 256 + p0 + p];
  }
  __syncthreads();

  if (t < 64) {  // FC1 (overlapped with splat phase)
    float a = fb1[t];
#pragma unroll 8
    for (int k = 0; k < 64; ++k) a += fw1[t * 64 + k] * scv[k];
    h1v[t] = fmaxf(a, 0.f);
  }
  pw_tile<64, 64, 0>(A, Bf, spw, spb, val[b], t);   // splat (no relu)
  __syncthreads();
  if (t < 64) {  // FC2 (overlapped with loc1 phase)
    float a = fb2[t];
#pragma unroll 8
    for (int k = 0; k < 64; ++k) a += fw2[t * 64 + k] * h1v[k];
    f2v[t] = fmaxf(a, 0.f);
  }
  pw_tile<64, 128, 1>(Bf, A, lw1, lb1, 0.f, t);     // loc1
  __syncthreads();
  pw_tile<128, 128, 1>(A, Bf, lw2, lb2, 0.f, t);    // loc2
  __syncthreads();
  pw_tile<128, 64, 1>(Bf, A, lw3, lb3, 0.f, t);     // loc3
  __syncthreads();

  {
    int pg = (t & 7) << 2;
    int og = t >> 3;  // NO = 3
    float acc[3][4];
#pragma unroll
    for (int j = 0; j < 3; ++j) {
      float bb = gb[og * 3 + j];
#pragma unroll
      for (int u = 0; u < 4; ++u) acc[j][u] = bb;
    }
#pragma unroll 4
    for (int k = 0; k < 64; k += 4) {
      float4 cc4 = *(const float4*)&f2v[k];
      float4 xv0 = *(const float4*)&A[k][pg];
      float4 xv1 = *(const float4*)&A[k + 1][pg];
      float4 xv2 = *(const float4*)&A[k + 2][pg];
      float4 xv3 = *(const float4*)&A[k + 3][pg];
      xv0.x = fmaxf(xv0.x + cc4.x, 0.f); xv0.y = fmaxf(xv0.y + cc4.x, 0.f);
      xv0.z = fmaxf(xv0.z + cc4.x, 0.f); xv0.w = fmaxf(xv0.w + cc4.x, 0.f);
      xv1.x = fmaxf(xv1.x + cc4.y, 0.f); xv1.y = fmaxf(xv1.y + cc4.y, 0.f);
      xv1.z = fmaxf(xv1.z + cc4.y, 0.f); xv1.w = fmaxf(xv1.w + cc4.y, 0.f);
      xv2.x = fmaxf(xv2.x + cc4.z, 0.f); xv2.y = fmaxf(xv2.y + cc4.z, 0.f);
      xv2.z = fmaxf(xv2.z + cc4.z, 0.f); xv2.w = fmaxf(xv2.w + cc4.z, 0.f);
      xv3.x = fmaxf(xv3.x + cc4.w, 0.f); xv3.y = fmaxf(xv3.y + cc4.w, 0.f);
      xv3.z = fmaxf(xv3.z + cc4.w, 0.f); xv3.w = fmaxf(xv3.w + cc4.w, 0.f);
#pragma unroll
      for (int j = 0; j < 3; ++j) {
        float4 wv = *(const float4*)&gw[(og * 3 + j) * 64 + k];
        acc[j][0] += wv.x * xv0.x + wv.y * xv1.x + wv.z * xv2.x + wv.w * xv3.x;
        acc[j][1] += wv.x * xv0.y + wv.y * xv1.y + wv.z * xv2.y + wv.w * xv3.y;
        acc[j][2] += wv.x * xv0.z + wv.y * xv1.z + wv.z * xv2.z + wv.w * xv3.z;
        acc[j][3] += wv.x * xv0.w + wv.y * xv1.w + wv.z * xv2.w + wv.w * xv3.w;
      }
    }
#pragma unroll
    for (int j = 0; j < 3; ++j) {
      int o = og * 3 + j;
      int l = o / 12, cc = o - l * 12;
#pragma unroll
      for (int u = 0; u < 4; ++u)
        gridt[(size_t)(((b * 8 + l) << 8) + p0 + pg + u) * 12 + cc] = acc[j][u];
    }
  }
}

// ---------------- guide + bilateral slice + affine apply (fused, LDS grid) ----
// Affine apply folded into the corner loop (exact by linearity): only 3 live
// accumulators across corners instead of acc[12] -> lower VGPR, higher occ.
#define ZST 200
__global__ __launch_bounds__(256, 6) void slice_k(
    const float* __restrict__ img, const float* __restrict__ gridt,
    const float* __restrict__ ccm_w, const float* __restrict__ ccm_b,
    const float* __restrict__ shifts, const float* __restrict__ slopes,
    const float* __restrict__ prw, const float* __restrict__ prb,
    float* __restrict__ out) {
  int blk = blockIdx.x;          // BATCH*1024
  int b = blk >> 10;
  int h = blk & 1023;
  int t = threadIdx.x;

  __shared__ float sg[8 * ZST];      // 6400 B
  __shared__ float2 lut[3][16];      // CS, CB

  float cy = (h + 0.5f) * 0.015625f - 0.5f;
  float y0f = floorf(cy);
  float wy = cy - y0f;
  int y0 = (int)y0f;
  int yi0 = min(max(y0, 0), 15), yi1 = min(max(y0 + 1, 0), 15);

  if (t < 48) {  // build curve LUT (prefix sums over 16 knots)
    int c = t >> 4, k = t & 15;
    float cs = 0.f, cbv = 0.f;
    for (int i = 0; i <= k; ++i) {
      float s = slopes[c * 16 + i];
      cs += s;
      cbv += s * shifts[c * 16 + i];
    }
    lut[c][k] = make_float2(cs, cbv);
  }

  // stage y-lerped grid: 8 slabs x 48 float4
  for (int i = t; i < 384; i += 256) {
    int z = i / 48;
    int e = i - z * 48;
    const float4* s0 =
        (const float4*)(gridt + (size_t)(((b * 8 + z) << 8) + (yi0 << 4)) * 12);
    const float4* s1 =
        (const float4*)(gridt + (size_t)(((b * 8 + z) << 8) + (yi1 << 4)) * 12);
    float4 a = s0[e], c = s1[e];
    float4 v = make_float4(a.x + wy * (c.x - a.x), a.y + wy * (c.y - a.y),
                           a.z + wy * (c.z - a.z), a.w + wy * (c.w - a.w));
    *((float4*)(sg + z * ZST) + e) = v;
  }
  __syncthreads();

  int pp = (h << 10) + (t << 2);
  const float* ib = img + (size_t)b * 3 * HH * WW;
  float4 R4 = *(const float4*)(ib + pp);
  float4 G4 = *(const float4*)(ib + HH * WW + pp);
  float4 B4 = *(const float4*)(ib + 2 * HH * WW + pp);
  float r_[4] = {R4.x, R4.y, R4.z, R4.w};
  float g_[4] = {G4.x, G4.y, G4.z, G4.w};
  float b_[4] = {B4.x, B4.y, B4.z, B4.w};

  float m0 = ccm_w[0], m1 = ccm_w[1], m2 = ccm_w[2];
  float m3 = ccm_w[3], m4 = ccm_w[4], m5 = ccm_w[5];
  float m6 = ccm_w[6], m7 = ccm_w[7], m8 = ccm_w[8];
  float c0 = ccm_b[0], c1 = ccm_b[1], c2 = ccm_b[2];
  float p0 = prw[0], p1 = prw[1], p2 = prw[2], pb = prb[0];

  float base0 = shifts[0], base1 = shifts[16], base2 = shifts[32];
  float inv0 = 1.0f / (shifts[1] - base0);
  float inv1 = 1.0f / (shifts[17] - base1);
  float inv2 = 1.0f / (shifts[33] - base2);

  float ro[4], go[4], bo[4];
#pragma unroll
  for (int j = 0; j < 4; ++j) {
    float r = r_[j], g = g_[j], bl = b_[j];
    float v0 = c0 + m0 * r + m1 * g + m2 * bl;
    float v1 = c1 + m3 * r + m4 * g + m5 * bl;
    float v2 = c2 + m6 * r + m7 * g + m8 * bl;

    float tv0 = fmaxf(v0, base0);
    float tv1 = fmaxf(v1, base1);
    float tv2 = fmaxf(v2, base2);
    int j0 = min((int)((tv0 - base0) * inv0), 15);
    int j1 = min((int)((tv1 - base1) * inv1), 15);
    int j2 = min((int)((tv2 - base2) * inv2), 15);
    float2 e0 = lut[0][j0];
    float2 e1 = lut[1][j1];
    float2 e2 = lut[2][j2];
    float f0 = e0.x * tv0 - e0.y;
    float f1 = e1.x * tv1 - e1.y;
    float f2 = e2.x * tv2 - e2.y;

    float gg = pb + p0 * f0 + p1 * f1 + p2 * f2;
    float guide = fminf(fmaxf(gg, 0.f), 1.f);

    int w = (t << 2) + j;
    float cx = (w + 0.5f) * 0.015625f - 0.5f;
    float x0f = floorf(cx);
    float wx = cx - x0f;
    int x0i = (int)x0f;
    int xi0 = min(max(x0i, 0), 15), xi1 = min(max(x0i + 1, 0), 15);

    float cz = guide * 8.0f - 0.5f;
    float z0f = floorf(cz);
    float wz = cz - z0f;
    int z0i = (int)z0f;
    int zi0 = min(max(z0i, 0), 7), zi1 = min(max(z0i + 1, 0), 7);

    int oz0 = zi0 * ZST, oz1 = zi1 * ZST;
    int ox0 = xi0 * 12, ox1 = xi1 * 12;
    float wz1 = wz, wz0 = 1.f - wz;
    float wx1 = wx, wx0 = 1.f - wx;

    float rr = 0.f, gg2 = 0.f, bb2 = 0.f;
#pragma unroll
    for (int dz = 0; dz < 2; ++dz) {
      int oz = dz ? oz1 : oz0;
      float wzz = dz ? wz1 : wz0;
#pragma unroll
      for (int dx = 0; dx < 2; ++dx) {
        int ox = dx ? ox1 : ox0;
        float wgt = wzz * (dx ? wx1 : wx0);
        const float* gp = sg + oz + ox;
        float4 a0 = *(const float4*)gp;
        float4 a1 = *(const float4*)(gp + 4);
        float4 a2 = *(const float4*)(gp + 8);
        rr  += wgt * (a0.x * r + a0.y * g + a0.z * bl + a0.w);
        gg2 += wgt * (a1.x * r + a1.y * g + a1.z * bl + a1.w);
        bb2 += wgt * (a2.x * r + a2.y * g + a2.z * bl + a2.w);
      }
    }
    ro[j] = rr;
    go[j] = gg2;
    bo[j] = bb2;
  }
  float* ob = out + (size_t)b * 3 * HH * WW;
  *(float4*)(ob + pp) = make_float4(ro[0], ro[1], ro[2], ro[3]);
  *(float4*)(ob + HH * WW + pp) = make_float4(go[0], go[1], go[2], go[3]);
  *(float4*)(ob + 2 * HH * WW + pp) = make_float4(bo[0], bo[1], bo[2], bo[3]);
}

extern "C" void kernel_launch(void* const* d_in, const int* in_sizes, int n_in,
                              void* d_out, int out_size, void* d_ws, size_t ws_size,
                              hipStream_t stream) {
  const float* image = (const float*)d_in[0];
  const float* val   = (const float*)d_in[1];
  const float* sw0 = (const float*)d_in[2];  const float* sb0 = (const float*)d_in[3];
  const float* sw1 = (const float*)d_in[4];  const float* sb1 = (const float*)d_in[5];
  const float* sw2 = (const float*)d_in[6];  const float* sb2 = (const float*)d_in[7];
  const float* sw3 = (const float*)d_in[8];  const float* sb3 = (const float*)d_in[9];
  const float* spw = (const float*)d_in[10]; const float* spb = (const float*)d_in[11];
  const float* lw1 = (const float*)d_in[12]; const float* lb1 = (const float*)d_in[13];
  const float* lw2 = (const float*)d_in[14]; const float* lb2 = (const float*)d_in[15];
  const float* lw3 = (const float*)d_in[16]; const float* lb3 = (const float*)d_in[17];
  const float* cw  = (const float*)d_in[18]; const float* cb  = (const float*)d_in[19];
  const float* fw1 = (const float*)d_in[20]; const float* fb1 = (const float*)d_in[21];
  const float* fw2 = (const float*)d_in[22]; const float* fb2 = (const float*)d_in[23];
  const float* gw  = (const float*)d_in[24]; const float* gb  = (const float*)d_in[25];
  const float* ccm_w = (const float*)d_in[26]; const float* ccm_b = (const float*)d_in[27];
  const float* shifts = (const float*)d_in[28]; const float* slopes = (const float*)d_in[29];
  const float* prw = (const float*)d_in[30]; const float* prb = (const float*)d_in[31];
  float* out = (float*)d_out;

  float* ws    = (float*)d_ws;
  float* x0    = ws;                  // 524288
  float* x1    = x0 + 524288;         // 262144
  float* x2    = x1 + 262144;         // 131072
  float* x3    = x2 + 131072;         // 65536
  float* cvec  = x3 + 65536;          // 256
  float* gridt = cvec + 256;          // 98304

  dsconv0_k<<<256, 256, 0, stream>>>(image, sw0, sb0, x0);
  conv_tile_k<8, 16, 128, 8><<<256, 256, 0, stream>>>(x0, sw1, sb1, x1);
  conv_tile_k<16, 32, 64, 4><<<256, 256, 0, stream>>>(x1, sw2, sb2, x2);
  conv_tile_k<32, 64, 32, 2><<<256, 256, 0, stream>>>(x2, sw3, sb3, x3);
  cpool_k<<<16, 256, 0, stream>>>(x3, spw, spb, val, cw, cb, cvec);
  mlp_k<<<32, 256, 0, stream>>>(x3, spw, spb, val, lw1, lb1, lw2, lb2, lw3, lb3,
                                cvec, fw1, fb1, fw2, fb2, gw, gb, gridt);
  slice_k<<<4096, 256, 0, stream>>>(image, gridt, ccm_w, ccm_b, shifts, slopes,
                                    prw, prb, out);
}